// Round 8
// baseline (341.888 us; speedup 1.0000x reference)
//
#include <hip/hip_runtime.h>
#include <hip/hip_bf16.h>

typedef __attribute__((ext_vector_type(8))) short bf16x8;
typedef __attribute__((ext_vector_type(4))) float f32x4;

__device__ __forceinline__ ushort f2bf(float f) {
  union { float f; unsigned u; } v; v.f = f;
  unsigned u = v.u;
  return (ushort)((u + 0x7FFFu + ((u >> 16) & 1u)) >> 16);
}
__device__ __forceinline__ float bf2f(ushort u) {
  union { unsigned u; float f; } v; v.u = ((unsigned)u) << 16;
  return v.f;
}
__device__ __forceinline__ float fsig(float x) {
  return __builtin_amdgcn_rcpf(1.0f + __expf(-x));
}
__device__ __forceinline__ float ftnh(float x) {
  float e = __expf(2.0f * x);
  return 1.0f - 2.0f * __builtin_amdgcn_rcpf(e + 1.0f);
}
__device__ __forceinline__ f32x4 MF(bf16x8 a, bf16x8 b, f32x4 c) {
  return __builtin_amdgcn_mfma_f32_16x16x32_bf16(a, b, c, 0, 0, 0);
}

// Repack layout (ushort units) in `wall`:
//  [0,131072)        whhrep [dir2][w8][lane64][frag16][8]
//  [131072,262144)   wihrep [dir2][wq4][j8][kk4][lane64][8]
//  [262144,294912)   linrep [w8][kk8][lane64][8]
//  [294912,425984)   emb_bf [1024][128]
__global__ __launch_bounds__(256) void repack_all2(
    const float* __restrict__ wihf, const float* __restrict__ whhf,
    const float* __restrict__ wihb, const float* __restrict__ whhb,
    const float* __restrict__ emb, const float* __restrict__ linw,
    ushort* __restrict__ wall) {
  int i = blockIdx.x * 256 + threadIdx.x;
  if (i < 131072) {
    int e = i & 7, f = (i >> 3) & 15, lane = (i >> 7) & 63, w = (i >> 13) & 7,
        d = (i >> 16) & 1;
    int nt = f >> 2, kk = f & 3;
    int pcol = w * 64 + nt * 16 + (lane & 15);
    int g = (pcol >> 4) & 3, h = (pcol >> 6) * 16 + (pcol & 15);
    int k = kk * 32 + (lane >> 4) * 8 + e;
    const float* src = d ? whhb : whhf;
    wall[i] = f2bf(src[(g * 128 + h) * 128 + k]);
  } else if (i < 262144) {
    int r = i - 131072;
    int e = r & 7, lane = (r >> 3) & 63, kk = (r >> 9) & 3, j = (r >> 11) & 7,
        wq = (r >> 14) & 3, d = (r >> 16) & 1;
    int pcol = wq * 128 + j * 16 + (lane & 15);
    int g = (pcol >> 4) & 3, h = (pcol >> 6) * 16 + (pcol & 15);
    int k = kk * 32 + (lane >> 4) * 8 + e;
    const float* src = d ? wihb : wihf;
    wall[i] = f2bf(src[(g * 128 + h) * 128 + k]);
  } else if (i < 294912) {
    int r = i - 262144;
    int e = r & 7, lane = (r >> 3) & 63, kk = (r >> 9) & 7, w = (r >> 12) & 7;
    int col = w * 16 + (lane & 15);
    int k = kk * 32 + (lane >> 4) * 8 + e;
    wall[i] = f2bf(linw[col * 256 + k]);
  } else if (i < 425984) {
    int r = i - 294912;
    wall[i] = f2bf(emb[r]);
  }
}

// x-gates of the 1024 vocab embeddings -> gxv[v][dir][hid][gate] bf16 (no bias)
__global__ __launch_bounds__(512) void gate_vocab(
    const ushort* __restrict__ emb_bf, const ushort* __restrict__ wihrep,
    ushort* __restrict__ gxv) {
  __shared__ __align__(16) ushort sT[2048];
  const int tid = threadIdx.x;
  const int w = tid >> 6, l = tid & 63, hlo = l & 15, lg = l >> 4;
  const int r0 = lg * 4, k0 = lg * 8;
  const int v0 = blockIdx.x * 16;
  {
    int row = tid >> 5, col0 = (tid & 31) * 4;
    *(ushort4*)(sT + row * 128 + (col0 ^ ((row & 7) << 3))) =
        *(const ushort4*)(emb_bf + (size_t)(v0 + row) * 128 + col0);
  }
  __syncthreads();
  const int d = w >> 2, wq = w & 3;
  const ushort* wp = wihrep + (size_t)(d * 4 + wq) * 16384 + l * 8;
  bf16x8 wf[32];
#pragma unroll
  for (int j = 0; j < 8; ++j)
#pragma unroll
    for (int kk = 0; kk < 4; ++kk)
      wf[j * 4 + kk] = *(const bf16x8*)(wp + j * 2048 + kk * 512);
  bf16x8 a[4];
#pragma unroll
  for (int kk = 0; kk < 4; ++kk)
    a[kk] = *(const bf16x8*)(sT + hlo * 128 + ((kk * 32 + k0) ^ ((hlo & 7) << 3)));
  f32x4 acc[8];
#pragma unroll
  for (int j = 0; j < 8; ++j) { f32x4 z = {0.f, 0.f, 0.f, 0.f}; acc[j] = z; }
#pragma unroll
  for (int kk = 0; kk < 4; ++kk)
#pragma unroll
    for (int j = 0; j < 8; ++j) acc[j] = MF(a[kk], wf[j * 4 + kk], acc[j]);
#pragma unroll
  for (int p = 0; p < 2; ++p)
#pragma unroll
    for (int rg = 0; rg < 4; ++rg) {
      int row = v0 + r0 + rg;
      int hid = (wq * 2 + p) * 16 + hlo;
      ushort4 q = {f2bf(acc[p * 4 + 0][rg]), f2bf(acc[p * 4 + 1][rg]),
                   f2bf(acc[p * 4 + 2][rg]), f2bf(acc[p * 4 + 3][rg])};
      *(ushort4*)(gxv + (size_t)row * 1024 + d * 512 + hid * 4) = q;
    }
}

// leaf scan over vocab: T=2, seq=[x,x] -> hL[2][1024][128]
__global__ __launch_bounds__(512) void leaf_scan(
    const ushort* __restrict__ gxv, const ushort* __restrict__ whhrep,
    const float* __restrict__ bihf, const float* __restrict__ bhhf,
    const float* __restrict__ bihb, const float* __restrict__ bhhb,
    ushort* __restrict__ hL) {
  __shared__ __align__(16) ushort sH[2048];
  const int tid = threadIdx.x;
  const int w = tid >> 6, l = tid & 63, hlo = l & 15, lg = l >> 4;
  const int r0 = lg * 4, k0 = lg * 8;
  const int hcol = w * 16 + hlo;
  const int d = blockIdx.y;
  const int v0 = blockIdx.x * 16;

  bf16x8 whh[16];
  {
    const ushort* p = whhrep + d * 65536 + w * 8192 + l * 128;
#pragma unroll
    for (int f = 0; f < 16; ++f) whh[f] = *(const bf16x8*)(p + f * 8);
  }
  const float* bih = d ? bihb : bihf;
  const float* bhh = d ? bhhb : bhhf;
  float bs[4];
#pragma unroll
  for (int nt = 0; nt < 4; ++nt) bs[nt] = bih[nt * 128 + hcol] + bhh[nt * 128 + hcol];

  ushort4 xg[4];
#pragma unroll
  for (int rg = 0; rg < 4; ++rg)
    xg[rg] = *(const ushort4*)(gxv + (size_t)(v0 + r0 + rg) * 1024 + d * 512 + hcol * 4);

  float c_st[4], hn[4];
#pragma unroll
  for (int rg = 0; rg < 4; ++rg) {
    float g0 = bf2f(((const ushort*)&xg[rg])[0]) + bs[0];
    float g2 = bf2f(((const ushort*)&xg[rg])[2]) + bs[2];
    float g3 = bf2f(((const ushort*)&xg[rg])[3]) + bs[3];
    float c = fsig(g0) * ftnh(g2);
    c_st[rg] = c;
    hn[rg] = fsig(g3) * ftnh(c);
  }
#pragma unroll
  for (int rg = 0; rg < 4; ++rg) {
    int rr = r0 + rg;
    sH[rr * 128 + (hcol ^ ((rr & 7) << 3))] = f2bf(hn[rg]);
  }
  __syncthreads();
  f32x4 a4[4];
#pragma unroll
  for (int rg = 0; rg < 4; ++rg)
#pragma unroll
    for (int nt = 0; nt < 4; ++nt)
      a4[nt][rg] = bf2f(((const ushort*)&xg[rg])[nt]) + bs[nt];
  bf16x8 ah[4];
#pragma unroll
  for (int kk = 0; kk < 4; ++kk)
    ah[kk] = *(const bf16x8*)(sH + hlo * 128 + ((kk * 32 + k0) ^ ((hlo & 7) << 3)));
#pragma unroll
  for (int kk = 0; kk < 4; ++kk)
#pragma unroll
    for (int nt = 0; nt < 4; ++nt) a4[nt] = MF(ah[kk], whh[nt * 4 + kk], a4[nt]);
#pragma unroll
  for (int rg = 0; rg < 4; ++rg) {
    float iv = fsig(a4[0][rg]);
    float fv = fsig(a4[1][rg]);
    float gv = ftnh(a4[2][rg]);
    float ov = fsig(a4[3][rg]);
    float c = fv * c_st[rg] + iv * gv;
    hn[rg] = ov * ftnh(c);
    hL[((size_t)d * 1024 + (v0 + r0 + rg)) * 128 + hcol] = f2bf(hn[rg]);
  }
}

// leaf finish: enc = tanh(head), gates(enc) -> gcv[1024][dir][hid][gate]
__global__ __launch_bounds__(512) void leaf_fin(
    const ushort* __restrict__ hL, const ushort* __restrict__ linrep,
    const float* __restrict__ linb, const ushort* __restrict__ wihrep,
    ushort* __restrict__ gcv) {
  __shared__ __align__(16) ushort sT[2048];
  const int tid = threadIdx.x;
  const int w = tid >> 6, l = tid & 63, hlo = l & 15, lg = l >> 4;
  const int r0 = lg * 4, k0 = lg * 8;
  const int v0 = blockIdx.x * 16;
  const float lb = linb[w * 16 + hlo];
  f32x4 hac = {lb, lb, lb, lb};
#pragma unroll
  for (int kk = 0; kk < 8; ++kk) {
    bf16x8 lf = *(const bf16x8*)(linrep + w * 4096 + kk * 512 + l * 8);
    bf16x8 af = *(const bf16x8*)(hL + ((size_t)(kk >> 2) * 1024 + v0 + hlo) * 128 +
                                 (kk & 3) * 32 + k0);
    hac = MF(af, lf, hac);
  }
#pragma unroll
  for (int rg = 0; rg < 4; ++rg) {
    int rr = r0 + rg;
    sT[rr * 128 + ((w * 16 + hlo) ^ ((rr & 7) << 3))] = f2bf(ftnh(hac[rg]));
  }
  __syncthreads();
  const int d = w >> 2, wq = w & 3;
  const ushort* wp = wihrep + (size_t)(d * 4 + wq) * 16384 + l * 8;
  bf16x8 wf[32];
#pragma unroll
  for (int j = 0; j < 8; ++j)
#pragma unroll
    for (int kk = 0; kk < 4; ++kk)
      wf[j * 4 + kk] = *(const bf16x8*)(wp + j * 2048 + kk * 512);
  bf16x8 a[4];
#pragma unroll
  for (int kk = 0; kk < 4; ++kk)
    a[kk] = *(const bf16x8*)(sT + hlo * 128 + ((kk * 32 + k0) ^ ((hlo & 7) << 3)));
  f32x4 acc[8];
#pragma unroll
  for (int j = 0; j < 8; ++j) { f32x4 z = {0.f, 0.f, 0.f, 0.f}; acc[j] = z; }
#pragma unroll
  for (int kk = 0; kk < 4; ++kk)
#pragma unroll
    for (int j = 0; j < 8; ++j) acc[j] = MF(a[kk], wf[j * 4 + kk], acc[j]);
#pragma unroll
  for (int p = 0; p < 2; ++p)
#pragma unroll
    for (int rg = 0; rg < 4; ++rg) {
      int row = v0 + r0 + rg;
      int hid = (wq * 2 + p) * 16 + hlo;
      ushort4 q = {f2bf(acc[p * 4 + 0][rg]), f2bf(acc[p * 4 + 1][rg]),
                   f2bf(acc[p * 4 + 2][rg]), f2bf(acc[p * 4 + 3][rg])};
      *(ushort4*)(gcv + (size_t)row * 1024 + d * 512 + hid * 4) = q;
    }
}

// L7 scan: x-gates + child-gates gathered from vocab tables -> h7
__global__ __launch_bounds__(512) void scan7_k(
    const int* __restrict__ labels, const ushort* __restrict__ gxv,
    const ushort* __restrict__ gcv, const ushort* __restrict__ whhrep,
    const float* __restrict__ bihf, const float* __restrict__ bhhf,
    const float* __restrict__ bihb, const float* __restrict__ bhhb,
    ushort* __restrict__ h7) {
  __shared__ __align__(16) ushort sH[2][2048];
  const int tid = threadIdx.x;
  const int w = tid >> 6, l = tid & 63, hlo = l & 15, lg = l >> 4;
  const int r0 = lg * 4, k0 = lg * 8;
  const int hcol = w * 16 + hlo;
  const int d = blockIdx.y;
  const int g = blockIdx.x;

  bf16x8 whh[16];
  {
    const ushort* p = whhrep + d * 65536 + w * 8192 + l * 128;
#pragma unroll
    for (int f = 0; f < 16; ++f) whh[f] = *(const bf16x8*)(p + f * 8);
  }
  const float* bih = d ? bihb : bihf;
  const float* bhh = d ? bhhb : bhhf;
  float bs[4];
#pragma unroll
  for (int nt = 0; nt < 4; ++nt) bs[nt] = bih[nt * 128 + hcol] + bhh[nt * 128 + hcol];

  int nn[4];
  ushort4 xg[4];
#pragma unroll
  for (int rg = 0; rg < 4; ++rg) {
    nn[rg] = g * 16 + r0 + rg;
    int xr = labels[5461 + nn[rg]];
    xg[rg] = *(const ushort4*)(gxv + (size_t)xr * 1024 + d * 512 + hcol * 4);
  }
  ushort4 cg[2][4];
  {
    const int ci = d ? 3 : 0;
#pragma unroll
    for (int rg = 0; rg < 4; ++rg) {
      int cl = labels[21845 + nn[rg] * 4 + ci];
      cg[1][rg] = *(const ushort4*)(gcv + (size_t)cl * 1024 + d * 512 + hcol * 4);
    }
  }
  float c_st[4], hn[4];
#pragma unroll
  for (int t = 0; t < 6; ++t) {
    const bool isx = (t == 0) || (t == 5);
    f32x4 a4[4];
#pragma unroll
    for (int rg = 0; rg < 4; ++rg) {
      ushort4 u = isx ? xg[rg] : cg[t & 1][rg];
#pragma unroll
      for (int nt = 0; nt < 4; ++nt)
        a4[nt][rg] = bf2f(((const ushort*)&u)[nt]) + bs[nt];
    }
    if (t >= 1 && t <= 3) {
      const int ci = d ? (3 - t) : t;
#pragma unroll
      for (int rg = 0; rg < 4; ++rg) {
        int cl = labels[21845 + nn[rg] * 4 + ci];
        cg[(t + 1) & 1][rg] =
            *(const ushort4*)(gcv + (size_t)cl * 1024 + d * 512 + hcol * 4);
      }
    }
    if (t > 0) {
      bf16x8 ah[4];
#pragma unroll
      for (int kk = 0; kk < 4; ++kk)
        ah[kk] = *(const bf16x8*)(&sH[(t + 1) & 1][0] + hlo * 128 +
                                  ((kk * 32 + k0) ^ ((hlo & 7) << 3)));
#pragma unroll
      for (int kk = 0; kk < 4; ++kk)
#pragma unroll
        for (int nt = 0; nt < 4; ++nt) a4[nt] = MF(ah[kk], whh[nt * 4 + kk], a4[nt]);
    }
#pragma unroll
    for (int rg = 0; rg < 4; ++rg) {
      float iv = fsig(a4[0][rg]);
      float fv = fsig(a4[1][rg]);
      float gv = ftnh(a4[2][rg]);
      float ov = fsig(a4[3][rg]);
      float c = (t == 0) ? (iv * gv) : (fv * c_st[rg] + iv * gv);
      c_st[rg] = c;
      hn[rg] = ov * ftnh(c);
    }
    if (t < 5) {
#pragma unroll
      for (int rg = 0; rg < 4; ++rg) {
        int rr = r0 + rg;
        sH[t & 1][rr * 128 + (hcol ^ ((rr & 7) << 3))] = f2bf(hn[rg]);
      }
      __syncthreads();
    } else {
#pragma unroll
      for (int rg = 0; rg < 4; ++rg)
        h7[((size_t)d * 16384 + nn[rg]) * 128 + hcol] = f2bf(hn[rg]);
    }
  }
}

// Generic "embedded finish + scan" for levels 6..0.
__device__ __forceinline__ void scan_embed(
    int g, int d, int cnt, const int* __restrict__ xlab,
    const ushort* __restrict__ gxv, const ushort* __restrict__ hsrc,
    const ushort* __restrict__ wihrep, const ushort* __restrict__ whhrep,
    const ushort* __restrict__ linrep, const float* __restrict__ linb,
    const float* __restrict__ bihf, const float* __restrict__ bhhf,
    const float* __restrict__ bihb, const float* __restrict__ bhhb,
    ushort* __restrict__ hdst, ushort* sG, ushort* sHb, ushort* sT) {
  const int tid = threadIdx.x;
  const int w = tid >> 6, l = tid & 63, hlo = l & 15, lg = l >> 4;
  const int r0 = lg * 4, k0 = lg * 8;
  const int hcol = w * 16 + hlo;
  const int ccnt = 4 * cnt;

  // ---- embedded finish of child level: head + gates(dir d) -> sG ----
  bf16x8 wf[16];
  {
    const ushort* wp = wihrep + (size_t)(d * 4 + (w >> 1)) * 16384 +
                       (size_t)((w & 1) * 4) * 2048 + l * 8;
#pragma unroll
    for (int jj = 0; jj < 4; ++jj)
#pragma unroll
      for (int kk = 0; kk < 4; ++kk)
        wf[jj * 4 + kk] = *(const bf16x8*)(wp + jj * 2048 + kk * 512);
  }
  const float lb = linb[hcol];
  const int ntile = min(4, (ccnt - g * 64 + 15) >> 4);
  for (int tt = 0; tt < ntile; ++tt) {
    f32x4 hac = {lb, lb, lb, lb};
    int cr = g * 64 + tt * 16 + hlo;
    if (cr >= ccnt) cr = ccnt - 1;
#pragma unroll
    for (int kk = 0; kk < 8; ++kk) {
      bf16x8 lf = *(const bf16x8*)(linrep + w * 4096 + kk * 512 + l * 8);
      bf16x8 af = *(const bf16x8*)(hsrc + ((size_t)(kk >> 2) * ccnt + cr) * 128 +
                                   (kk & 3) * 32 + k0);
      hac = MF(af, lf, hac);
    }
    __syncthreads();
#pragma unroll
    for (int rg = 0; rg < 4; ++rg) {
      int rr = r0 + rg;
      sT[rr * 128 + (hcol ^ ((rr & 7) << 3))] = f2bf(ftnh(hac[rg]));
    }
    __syncthreads();
    bf16x8 a[4];
#pragma unroll
    for (int kk = 0; kk < 4; ++kk)
      a[kk] = *(const bf16x8*)(sT + hlo * 128 + ((kk * 32 + k0) ^ ((hlo & 7) << 3)));
    f32x4 acc[4];
#pragma unroll
    for (int jj = 0; jj < 4; ++jj) { f32x4 z = {0.f, 0.f, 0.f, 0.f}; acc[jj] = z; }
#pragma unroll
    for (int kk = 0; kk < 4; ++kk)
#pragma unroll
      for (int jj = 0; jj < 4; ++jj) acc[jj] = MF(a[kk], wf[jj * 4 + kk], acc[jj]);
    const int hid = (w >> 1) * 32 + (w & 1) * 16 + hlo;
#pragma unroll
    for (int rg = 0; rg < 4; ++rg) {
      int lrow = tt * 16 + r0 + rg;
      int sw = ((((lrow >> 4) & 3) ^ ((lrow >> 2) & 3)) << 4);
      ushort4 q = {f2bf(acc[0][rg]), f2bf(acc[1][rg]), f2bf(acc[2][rg]),
                   f2bf(acc[3][rg])};
      *(ushort4*)(sG + lrow * 512 + ((hid * 4) ^ sw)) = q;
    }
  }
  __syncthreads();

  // ---- scan ----
  bf16x8 whh[16];
  {
    const ushort* p = whhrep + d * 65536 + w * 8192 + l * 128;
#pragma unroll
    for (int f = 0; f < 16; ++f) whh[f] = *(const bf16x8*)(p + f * 8);
  }
  const float* bih = d ? bihb : bihf;
  const float* bhh = d ? bhhb : bhhf;
  float bs[4];
#pragma unroll
  for (int nt = 0; nt < 4; ++nt) bs[nt] = bih[nt * 128 + hcol] + bhh[nt * 128 + hcol];

  int nn[4];
  ushort4 xg[4];
#pragma unroll
  for (int rg = 0; rg < 4; ++rg) {
    nn[rg] = g * 16 + r0 + rg;
    int cl = nn[rg] < cnt ? nn[rg] : cnt - 1;
    int xr = xlab[cl];
    xg[rg] = *(const ushort4*)(gxv + (size_t)xr * 1024 + d * 512 + hcol * 4);
  }
  float c_st[4], hn[4];
#pragma unroll
  for (int t = 0; t < 6; ++t) {
    const bool isx = (t == 0) || (t == 5);
    f32x4 a4[4];
#pragma unroll
    for (int rg = 0; rg < 4; ++rg) {
      ushort4 u;
      if (isx) {
        u = xg[rg];
      } else {
        const int ci = d ? (4 - t) : (t - 1);
        int lrow = (r0 + rg) * 4 + ci;
        int sw = ((((lrow >> 4) & 3) ^ ((lrow >> 2) & 3)) << 4);
        u = *(const ushort4*)(sG + lrow * 512 + ((hcol * 4) ^ sw));
      }
#pragma unroll
      for (int nt = 0; nt < 4; ++nt)
        a4[nt][rg] = bf2f(((const ushort*)&u)[nt]) + bs[nt];
    }
    if (t > 0) {
      bf16x8 ah[4];
#pragma unroll
      for (int kk = 0; kk < 4; ++kk)
        ah[kk] = *(const bf16x8*)(sHb + ((t + 1) & 1) * 2048 + hlo * 128 +
                                  ((kk * 32 + k0) ^ ((hlo & 7) << 3)));
#pragma unroll
      for (int kk = 0; kk < 4; ++kk)
#pragma unroll
        for (int nt = 0; nt < 4; ++nt) a4[nt] = MF(ah[kk], whh[nt * 4 + kk], a4[nt]);
    }
#pragma unroll
    for (int rg = 0; rg < 4; ++rg) {
      float iv = fsig(a4[0][rg]);
      float fv = fsig(a4[1][rg]);
      float gv = ftnh(a4[2][rg]);
      float ov = fsig(a4[3][rg]);
      float c = (t == 0) ? (iv * gv) : (fv * c_st[rg] + iv * gv);
      c_st[rg] = c;
      hn[rg] = ov * ftnh(c);
    }
    if (t < 5) {
#pragma unroll
      for (int rg = 0; rg < 4; ++rg) {
        int rr = r0 + rg;
        sHb[(t & 1) * 2048 + rr * 128 + (hcol ^ ((rr & 7) << 3))] = f2bf(hn[rg]);
      }
      __syncthreads();
    } else {
#pragma unroll
      for (int rg = 0; rg < 4; ++rg)
        if (nn[rg] < cnt)
          hdst[((size_t)d * cnt + nn[rg]) * 128 + hcol] = f2bf(hn[rg]);
    }
  }
}

// Striped global barrier: arrivals over 16 cachelines, broadcast epoch flag.
__device__ __forceinline__ void gbar(unsigned* bar, int epoch, unsigned nblocks) {
  __syncthreads();
  if (threadIdx.x == 0) {
    __builtin_amdgcn_fence(__ATOMIC_RELEASE, "agent");
    __hip_atomic_fetch_add(&bar[(blockIdx.x & 15) * 32], 1u, __ATOMIC_RELAXED,
                           __HIP_MEMORY_SCOPE_AGENT);
    unsigned* flag = &bar[512];
    if (blockIdx.x == 0) {
      unsigned sum;
      do {
        sum = 0;
#pragma unroll
        for (int i = 0; i < 16; ++i)
          sum += __hip_atomic_load(&bar[i * 32], __ATOMIC_RELAXED,
                                   __HIP_MEMORY_SCOPE_AGENT);
      } while (sum < nblocks * (unsigned)epoch);
      __hip_atomic_store(flag, (unsigned)epoch, __ATOMIC_RELAXED,
                         __HIP_MEMORY_SCOPE_AGENT);
    } else {
      while (__hip_atomic_load(flag, __ATOMIC_RELAXED,
                               __HIP_MEMORY_SCOPE_AGENT) < (unsigned)epoch)
        __builtin_amdgcn_s_sleep(1);
    }
    __builtin_amdgcn_fence(__ATOMIC_ACQUIRE, "agent");
  }
  __syncthreads();
}

// Levels 6..0 + final head. Grid 256 blocks (1/CU co-resident guaranteed).
// Levels 6,5,4,3 parallel (barrier after each); levels 2,1,0 + head in block 0.
__global__ __launch_bounds__(512) void coop_tail2(
    const int* __restrict__ labels, const ushort* __restrict__ gxv,
    ushort* __restrict__ hpool, const ushort* __restrict__ wihrep,
    const ushort* __restrict__ whhrep, const ushort* __restrict__ linrep,
    const float* __restrict__ linb, const float* __restrict__ bihf,
    const float* __restrict__ bhhf, const float* __restrict__ bihb,
    const float* __restrict__ bhhb, float* __restrict__ outp,
    unsigned* __restrict__ bar) {
  __shared__ __align__(16) ushort sG[32768];
  __shared__ __align__(16) ushort sH[2][2048];
  __shared__ __align__(16) ushort sT[2048];
  const int pcnt[4] = {4096, 1024, 256, 64};
  const int pxoff[4] = {1365, 341, 85, 21};
  const unsigned psrc[4] = {0u, 4194304u, 5242880u, 5505024u};
  const unsigned pdst[4] = {4194304u, 5242880u, 5505024u, 5570560u};
  for (int p = 0; p < 4; ++p) {
    const int c = pcnt[p];
    const int ntasks = 2 * (c >> 4);
    for (int task = blockIdx.x; task < ntasks; task += gridDim.x)
      scan_embed(task >> 1, task & 1, c, labels + pxoff[p], gxv,
                 hpool + psrc[p], wihrep, whhrep, linrep, linb, bihf, bhhf,
                 bihb, bhhb, hpool + pdst[p], sG, &sH[0][0], sT);
    gbar(bar, p + 1, gridDim.x);
  }
  if (blockIdx.x != 0) return;

  const int scnt[3] = {16, 4, 1};
  const int sxoff[3] = {5, 1, 0};
  const unsigned ssrc[3] = {5570560u, 5586944u, 5591040u};
  const unsigned sdst[3] = {5586944u, 5591040u, 5592064u};
  for (int p = 0; p < 3; ++p) {
    for (int d = 0; d < 2; ++d)
      scan_embed(0, d, scnt[p], labels + sxoff[p], gxv, hpool + ssrc[p],
                 wihrep, whhrep, linrep, linb, bihf, bhhf, bihb, bhhb,
                 hpool + sdst[p], sG, &sH[0][0], sT);
    __syncthreads();
    __builtin_amdgcn_fence(__ATOMIC_ACQ_REL, "agent");
    __syncthreads();
  }
  // final head from h0
  const int tid = threadIdx.x;
  const int w = tid >> 6, l = tid & 63, hlo = l & 15, lg = l >> 4;
  const ushort* h0 = hpool + 5592064u;
  const float lb = linb[w * 16 + hlo];
  f32x4 hac = {lb, lb, lb, lb};
#pragma unroll
  for (int kk = 0; kk < 8; ++kk) {
    bf16x8 lf = *(const bf16x8*)(linrep + w * 4096 + kk * 512 + l * 8);
    bf16x8 af =
        *(const bf16x8*)(h0 + (size_t)(kk >> 2) * 128 + (kk & 3) * 32 + lg * 8);
    hac = MF(af, lf, hac);
  }
  if (lg == 0) outp[w * 16 + hlo] = ftnh(hac[0]);
}

extern "C" void kernel_launch(void* const* d_in, const int* in_sizes, int n_in,
                              void* d_out, int out_size, void* d_ws, size_t ws_size,
                              hipStream_t stream) {
  const int* labels = (const int*)d_in[0];
  const float* emb = (const float*)d_in[1];
  const float* w_ih_f = (const float*)d_in[2];
  const float* w_hh_f = (const float*)d_in[3];
  const float* b_ih_f = (const float*)d_in[4];
  const float* b_hh_f = (const float*)d_in[5];
  const float* w_ih_b = (const float*)d_in[6];
  const float* w_hh_b = (const float*)d_in[7];
  const float* b_ih_b = (const float*)d_in[8];
  const float* b_hh_b = (const float*)d_in[9];
  const float* lin_w = (const float*)d_in[10];
  const float* lin_b = (const float*)d_in[11];
  float* out = (float*)d_out;

  unsigned* bar = (unsigned*)d_ws;     // 4096 B barrier area
  ushort* W = (ushort*)d_ws;
  ushort* gxv = W + 2048;              // 1024*1024
  ushort* gcv = gxv + 1048576;         // 1024*1024
  ushort* hpool = gcv + 1048576;       // 5,592,320 (h7..h0)
  ushort* hL = hpool + 5592320;        // 2*1024*128
  ushort* wall = hL + 262144;          // 425,984
  ushort* whhrep = wall;
  ushort* wihrep = wall + 131072;
  ushort* linrep = wall + 262144;
  ushort* emb_bf = wall + 294912;
  ushort* h7 = hpool;                  // [2][16384][128]

  hipMemsetAsync(bar, 0, 4096, stream);
  repack_all2<<<1664, 256, 0, stream>>>(w_ih_f, w_hh_f, w_ih_b, w_hh_b, emb,
                                        lin_w, wall);
  gate_vocab<<<64, 512, 0, stream>>>(emb_bf, wihrep, gxv);
  leaf_scan<<<dim3(64, 2), 512, 0, stream>>>(gxv, whhrep, b_ih_f, b_hh_f,
                                             b_ih_b, b_hh_b, hL);
  leaf_fin<<<64, 512, 0, stream>>>(hL, linrep, lin_b, wihrep, gcv);
  scan7_k<<<dim3(1024, 2), 512, 0, stream>>>(labels, gxv, gcv, whhrep, b_ih_f,
                                             b_hh_f, b_ih_b, b_hh_b, h7);
  coop_tail2<<<256, 512, 0, stream>>>(labels, gxv, hpool, wihrep, whhrep,
                                      linrep, lin_b, b_ih_f, b_hh_f, b_ih_b,
                                      b_hh_b, out, bar);
}